// Round 3
// baseline (749.034 us; speedup 1.0000x reference)
//
#include <hip/hip_runtime.h>
#include <cstdint>

#define CIN 128
#define NH 8
#define CH 32
#define LDQ 1024   // qkvg row stride (q|k|v|g, 4*256)

typedef short bf16x8 __attribute__((ext_vector_type(8)));
typedef float f32x4 __attribute__((ext_vector_type(4)));

__device__ __forceinline__ short f2bf(float f) {
  union { float f; unsigned u; } v; v.f = f;
  unsigned r = (v.u + 0x7FFFu + ((v.u >> 16) & 1u)) >> 16;   // RNE
  return (short)r;
}

// ---------------- prep: detect mask element width ----------------
__global__ __launch_bounds__(256) void detect_mask(
    const unsigned char* __restrict__ m, unsigned int* __restrict__ flag)
{
  __shared__ int viol;
  if (threadIdx.x == 0) viol = 0;
  __syncthreads();
  int v = 0;
  const int base = threadIdx.x * 256;
  for (int j = 0; j < 256; ++j) {
    int i = base + j;
    unsigned char b = m[i];
    v |= ((i & 3) ? (b != 0) : (b > 1)) ? 1 : 0;
  }
  if (v) atomicOr(&viol, 1);
  __syncthreads();
  if (threadIdx.x == 0) *flag = viol ? 0u : 1u;
}

// ---------------- fused QKVG projection (per chunk of rows) ----------------
__global__ __launch_bounds__(256) void proj_qkvg(
    const float* __restrict__ x,
    const float* __restrict__ Wq, const float* __restrict__ Wk,
    const float* __restrict__ Wv, const float* __restrict__ Wg,
    const float* __restrict__ bg, float* __restrict__ qkvg)
{
  __shared__ float At[64][132];
  __shared__ float Wl[64][68];
  const int tid = threadIdx.x;
  const int tx = tid & 15, ty = tid >> 4;
  const int n0 = blockIdx.x * 64;
  const int row0 = blockIdx.y * 128;
  const int seg = n0 >> 8;                  // 0=q 1=k 2=v 3=g
  const float* W = (seg == 0) ? Wq : (seg == 1) ? Wk : (seg == 2) ? Wv : Wg;
  const int nw = n0 & 255;

  float acc[8][4];
#pragma unroll
  for (int i = 0; i < 8; ++i)
#pragma unroll
    for (int j = 0; j < 4; ++j) acc[i][j] = 0.f;

  for (int k0 = 0; k0 < 128; k0 += 64) {
#pragma unroll
    for (int j = 0; j < 8; ++j) {
      int f = tid + j * 256;
      int r = f >> 4, kv = f & 15;
      const float4 a = *(const float4*)(x + (size_t)(row0 + r) * CIN + k0 + kv * 4);
      At[kv * 4 + 0][r] = a.x; At[kv * 4 + 1][r] = a.y;
      At[kv * 4 + 2][r] = a.z; At[kv * 4 + 3][r] = a.w;
    }
#pragma unroll
    for (int j = 0; j < 4; ++j) {
      int f = tid + j * 256;
      int kr = f >> 4, nv = f & 15;
      *(float4*)&Wl[kr][nv * 4] = *(const float4*)(W + (k0 + kr) * 256 + nw + nv * 4);
    }
    __syncthreads();
#pragma unroll 16
    for (int k = 0; k < 64; ++k) {
      float4 a0 = *(const float4*)&At[k][ty * 8];
      float4 a1 = *(const float4*)&At[k][ty * 8 + 4];
      float4 w  = *(const float4*)&Wl[k][tx * 4];
      acc[0][0] += a0.x * w.x; acc[0][1] += a0.x * w.y; acc[0][2] += a0.x * w.z; acc[0][3] += a0.x * w.w;
      acc[1][0] += a0.y * w.x; acc[1][1] += a0.y * w.y; acc[1][2] += a0.y * w.z; acc[1][3] += a0.y * w.w;
      acc[2][0] += a0.z * w.x; acc[2][1] += a0.z * w.y; acc[2][2] += a0.z * w.z; acc[2][3] += a0.z * w.w;
      acc[3][0] += a0.w * w.x; acc[3][1] += a0.w * w.y; acc[3][2] += a0.w * w.z; acc[3][3] += a0.w * w.w;
      acc[4][0] += a1.x * w.x; acc[4][1] += a1.x * w.y; acc[4][2] += a1.x * w.z; acc[4][3] += a1.x * w.w;
      acc[5][0] += a1.y * w.x; acc[5][1] += a1.y * w.y; acc[5][2] += a1.y * w.z; acc[5][3] += a1.y * w.w;
      acc[6][0] += a1.z * w.x; acc[6][1] += a1.z * w.y; acc[6][2] += a1.z * w.z; acc[6][3] += a1.z * w.w;
      acc[7][0] += a1.w * w.x; acc[7][1] += a1.w * w.y; acc[7][2] += a1.w * w.z; acc[7][3] += a1.w * w.w;
    }
    __syncthreads();
  }

  const float qscale = 0.17677669529663689f;  // 1/sqrt(32)
  float4 bgv = make_float4(0.f, 0.f, 0.f, 0.f);
  if (seg == 3) bgv = *(const float4*)(bg + nw + tx * 4);
#pragma unroll
  for (int i = 0; i < 8; ++i) {
    int row = row0 + ty * 8 + i;
    float4 v = make_float4(acc[i][0], acc[i][1], acc[i][2], acc[i][3]);
    if (seg == 0) {
      v.x *= qscale; v.y *= qscale; v.z *= qscale; v.w *= qscale;
    } else if (seg == 3) {
      v.x = 1.f / (1.f + __expf(-(v.x + bgv.x)));
      v.y = 1.f / (1.f + __expf(-(v.y + bgv.y)));
      v.z = 1.f / (1.f + __expf(-(v.z + bgv.z)));
      v.w = 1.f / (1.f + __expf(-(v.w + bgv.w)));
    }
    *(float4*)(qkvg + (size_t)row * LDQ + n0 + tx * 4) = v;
  }
}

// ---------------- MFMA flash attention + gating ----------------
// block = (h, srow-in-chunk), 256 threads = 4 waves; wave owns 64 q rows.
// bf16 MFMA 16x16x32. Pass A: rowmax of raw QK^T (no bias needed: softmax
// shift-invariant, exp args stay bounded). Pass B: S+bias, mask, exp, P->LDS,
// PV MFMA. Gated output written to the q slot of qkvg (fp32).
__global__ __launch_bounds__(256) void attn(
    float* __restrict__ qkvg, const float* __restrict__ bias,
    const void* __restrict__ maskraw, const unsigned int* __restrict__ flagp,
    int srow0)
{
  // shorts: kL [256 keys][stride 40] @0 ; vT [32 c][stride 264] @10240 ;
  //         pL per-wave [64 q][stride 40] @18688 + w*2560.  57856 B total.
  __shared__ __align__(16) short lds16[28928];
  const int tid = threadIdx.x;
  const int h = blockIdx.x;
  const int srow = srow0 + blockIdx.y;
  const int lane = tid & 63, w = tid >> 6;
  const int g = lane >> 4, c16 = lane & 15;
  float* rowbase = qkvg + (size_t)blockIdx.y * (256 * LDQ);

  // ---- mask row -> 8x u32 bits (shared via LDS scratch in pL region) ----
  const unsigned int fl = *flagp;
  int mv = fl ? ((const int*)maskraw)[srow * 256 + tid]
              : (int)((const unsigned char*)maskraw)[srow * 256 + tid];
  unsigned long long bb = __ballot(mv != 0);
  unsigned int* scratch = (unsigned int*)&lds16[18688];
  if (lane == 0) {
    scratch[w * 2 + 0] = (unsigned int)bb;
    scratch[w * 2 + 1] = (unsigned int)(bb >> 32);
  }
  __syncthreads();
  unsigned int mb[8];
#pragma unroll
  for (int j = 0; j < 8; ++j) mb[j] = scratch[j];
  __syncthreads();

  // ---- stage k -> kL[key][c], v -> vT[c][key] (fp32 -> bf16) ----
#pragma unroll
  for (int j = 0; j < 8; ++j) {
    int f = tid + j * 256;
    int key = f >> 3, cv = f & 7;
    const float* kp = rowbase + (size_t)key * LDQ + 256 + h * CH + cv * 4;
    float4 kd = *(const float4*)kp;
    float4 vd = *(const float4*)(kp + 256);
    short4 kb;
    kb.x = f2bf(kd.x); kb.y = f2bf(kd.y); kb.z = f2bf(kd.z); kb.w = f2bf(kd.w);
    *(short4*)&lds16[key * 40 + cv * 4] = kb;
    lds16[10240 + (cv * 4 + 0) * 264 + key] = f2bf(vd.x);
    lds16[10240 + (cv * 4 + 1) * 264 + key] = f2bf(vd.y);
    lds16[10240 + (cv * 4 + 2) * 264 + key] = f2bf(vd.z);
    lds16[10240 + (cv * 4 + 3) * 264 + key] = f2bf(vd.w);
  }

  // ---- q A-frags (global fp32 -> bf16 regs), 4 row-tiles of 16 ----
  const int qb = w * 64;
  bf16x8 qf[4];
#pragma unroll
  for (int rt = 0; rt < 4; ++rt) {
    const float* qp = rowbase + (size_t)(qb + rt * 16 + c16) * LDQ + h * CH + g * 8;
    float4 a = *(const float4*)qp;
    float4 b = *(const float4*)(qp + 4);
    bf16x8 qv;
    qv[0] = f2bf(a.x); qv[1] = f2bf(a.y); qv[2] = f2bf(a.z); qv[3] = f2bf(a.w);
    qv[4] = f2bf(b.x); qv[5] = f2bf(b.y); qv[6] = f2bf(b.z); qv[7] = f2bf(b.w);
    qf[rt] = qv;
  }
  __syncthreads();

  const f32x4 zero4 = {0.f, 0.f, 0.f, 0.f};

  // ---- pass A: rowmax of raw QK^T ----
  float m_[4][4];
#pragma unroll
  for (int rt = 0; rt < 4; ++rt)
#pragma unroll
    for (int i = 0; i < 4; ++i) m_[rt][i] = -1e30f;

  for (int kt = 0; kt < 16; ++kt) {
    bf16x8 kf = *(const bf16x8*)&lds16[(kt * 16 + c16) * 40 + g * 8];
#pragma unroll
    for (int rt = 0; rt < 4; ++rt) {
      f32x4 S = __builtin_amdgcn_mfma_f32_16x16x32_bf16(qf[rt], kf, zero4, 0, 0, 0);
#pragma unroll
      for (int i = 0; i < 4; ++i) m_[rt][i] = fmaxf(m_[rt][i], S[i]);
    }
  }
#pragma unroll
  for (int rt = 0; rt < 4; ++rt)
#pragma unroll
    for (int i = 0; i < 4; ++i) {
      float v = m_[rt][i];
      v = fmaxf(v, __shfl_xor(v, 1));
      v = fmaxf(v, __shfl_xor(v, 2));
      v = fmaxf(v, __shfl_xor(v, 4));
      v = fmaxf(v, __shfl_xor(v, 8));
      m_[rt][i] = v;
    }

  // ---- pass B: P = mask ? exp(S + bias - m) : 0 ; O += P @ V ----
  float l_[4][4];
#pragma unroll
  for (int rt = 0; rt < 4; ++rt)
#pragma unroll
    for (int i = 0; i < 4; ++i) l_[rt][i] = 0.f;
  f32x4 O[4][2];
#pragma unroll
  for (int rt = 0; rt < 4; ++rt) { O[rt][0] = zero4; O[rt][1] = zero4; }

  const int pbase = 18688 + w * 2560;
  const float* bh = bias + (size_t)h * 65536;

  for (int ch = 0; ch < 8; ++ch) {
#pragma unroll
    for (int t2 = 0; t2 < 2; ++t2) {
      const int kt = ch * 2 + t2;
      bf16x8 kf = *(const bf16x8*)&lds16[(kt * 16 + c16) * 40 + g * 8];
      const unsigned int bit = (mb[kt >> 1] >> (((kt & 1) << 4) + c16)) & 1u;
#pragma unroll
      for (int rt = 0; rt < 4; ++rt) {
        f32x4 S = __builtin_amdgcn_mfma_f32_16x16x32_bf16(qf[rt], kf, zero4, 0, 0, 0);
        const float* bp = bh + (size_t)(qb + rt * 16 + g * 4) * 256 + kt * 16 + c16;
#pragma unroll
        for (int i = 0; i < 4; ++i) {
          float s = S[i] + bp[i * 256];
          float p = bit ? __expf(s - m_[rt][i]) : 0.f;
          l_[rt][i] += p;
          lds16[pbase + (rt * 16 + g * 4 + i) * 40 + t2 * 16 + c16] = f2bf(p);
        }
      }
    }
    __syncthreads();
    bf16x8 vf0 = *(const bf16x8*)&lds16[10240 + (c16) * 264 + ch * 32 + g * 8];
    bf16x8 vf1 = *(const bf16x8*)&lds16[10240 + (16 + c16) * 264 + ch * 32 + g * 8];
#pragma unroll
    for (int rt = 0; rt < 4; ++rt) {
      bf16x8 pf = *(const bf16x8*)&lds16[pbase + (rt * 16 + c16) * 40 + g * 8];
      O[rt][0] = __builtin_amdgcn_mfma_f32_16x16x32_bf16(pf, vf0, O[rt][0], 0, 0, 0);
      O[rt][1] = __builtin_amdgcn_mfma_f32_16x16x32_bf16(pf, vf1, O[rt][1], 0, 0, 0);
    }
    __syncthreads();
  }

#pragma unroll
  for (int rt = 0; rt < 4; ++rt)
#pragma unroll
    for (int i = 0; i < 4; ++i) {
      float v = l_[rt][i];
      v += __shfl_xor(v, 1);
      v += __shfl_xor(v, 2);
      v += __shfl_xor(v, 4);
      v += __shfl_xor(v, 8);
      l_[rt][i] = v;
    }

  // ---- epilogue: O/l * gate -> q slot ----
#pragma unroll
  for (int rt = 0; rt < 4; ++rt)
#pragma unroll
    for (int i = 0; i < 4; ++i) {
      float inv = 1.f / l_[rt][i];
      float* orow = rowbase + (size_t)(qb + rt * 16 + g * 4 + i) * LDQ;
#pragma unroll
      for (int oc = 0; oc < 2; ++oc) {
        int c = oc * 16 + c16;
        float gv = orow[768 + h * CH + c];
        orow[h * CH + c] = O[rt][oc][i] * inv * gv;
      }
    }
}

// ---------------- output projection: out = oG @ Wo + bo (per chunk) ----------------
__global__ __launch_bounds__(256) void out_proj(
    const float* __restrict__ og, const float* __restrict__ Wo,
    const float* __restrict__ bo, float* __restrict__ out)
{
  __shared__ float At[64][132];
  __shared__ float Wl[64][68];
  const int tid = threadIdx.x;
  const int tx = tid & 15, ty = tid >> 4;
  const int n0 = blockIdx.x * 64;
  const int row0 = blockIdx.y * 128;

  float acc[8][4];
#pragma unroll
  for (int i = 0; i < 8; ++i)
#pragma unroll
    for (int j = 0; j < 4; ++j) acc[i][j] = 0.f;

  for (int k0 = 0; k0 < 256; k0 += 64) {
#pragma unroll
    for (int j = 0; j < 8; ++j) {
      int f = tid + j * 256;
      int r = f >> 4, kv = f & 15;
      const float4 a = *(const float4*)(og + (size_t)(row0 + r) * LDQ + k0 + kv * 4);
      At[kv * 4 + 0][r] = a.x; At[kv * 4 + 1][r] = a.y;
      At[kv * 4 + 2][r] = a.z; At[kv * 4 + 3][r] = a.w;
    }
#pragma unroll
    for (int j = 0; j < 4; ++j) {
      int f = tid + j * 256;
      int kr = f >> 4, nv = f & 15;
      *(float4*)&Wl[kr][nv * 4] = *(const float4*)(Wo + (k0 + kr) * 128 + n0 + nv * 4);
    }
    __syncthreads();
#pragma unroll 16
    for (int k = 0; k < 64; ++k) {
      float4 a0 = *(const float4*)&At[k][ty * 8];
      float4 a1 = *(const float4*)&At[k][ty * 8 + 4];
      float4 w  = *(const float4*)&Wl[k][tx * 4];
      acc[0][0] += a0.x * w.x; acc[0][1] += a0.x * w.y; acc[0][2] += a0.x * w.z; acc[0][3] += a0.x * w.w;
      acc[1][0] += a0.y * w.x; acc[1][1] += a0.y * w.y; acc[1][2] += a0.y * w.z; acc[1][3] += a0.y * w.w;
      acc[2][0] += a0.z * w.x; acc[2][1] += a0.z * w.y; acc[2][2] += a0.z * w.z; acc[2][3] += a0.z * w.w;
      acc[3][0] += a0.w * w.x; acc[3][1] += a0.w * w.y; acc[3][2] += a0.w * w.z; acc[3][3] += a0.w * w.w;
      acc[4][0] += a1.x * w.x; acc[4][1] += a1.x * w.y; acc[4][2] += a1.x * w.z; acc[4][3] += a1.x * w.w;
      acc[5][0] += a1.y * w.x; acc[5][1] += a1.y * w.y; acc[5][2] += a1.y * w.z; acc[5][3] += a1.y * w.w;
      acc[6][0] += a1.z * w.x; acc[6][1] += a1.z * w.y; acc[6][2] += a1.z * w.z; acc[6][3] += a1.z * w.w;
      acc[7][0] += a1.w * w.x; acc[7][1] += a1.w * w.y; acc[7][2] += a1.w * w.z; acc[7][3] += a1.w * w.w;
    }
    __syncthreads();
  }

  float4 bv = *(const float4*)(bo + n0 + tx * 4);
#pragma unroll
  for (int i = 0; i < 8; ++i) {
    int row = row0 + ty * 8 + i;
    float4 v = make_float4(acc[i][0] + bv.x, acc[i][1] + bv.y,
                           acc[i][2] + bv.z, acc[i][3] + bv.w);
    *(float4*)(out + (size_t)row * CIN + n0 + tx * 4) = v;
  }
}

extern "C" void kernel_launch(void* const* d_in, const int* in_sizes, int n_in,
                              void* d_out, int out_size, void* d_ws, size_t ws_size,
                              hipStream_t stream) {
  const float* x    = (const float*)d_in[0];
  const float* bias = (const float*)d_in[1];
  const void*  mask = d_in[2];
  const float* Wq   = (const float*)d_in[3];
  const float* Wk   = (const float*)d_in[4];
  const float* Wv   = (const float*)d_in[5];
  const float* Wo   = (const float*)d_in[6];
  const float* bo   = (const float*)d_in[7];
  const float* Wg   = (const float*)d_in[8];
  const float* bg   = (const float*)d_in[9];
  float* out = (float*)d_out;

  // ws layout: [flag 256 B][qkvg chunk]
  unsigned int* flag = (unsigned int*)d_ws;
  float* qkvg = (float*)((char*)d_ws + 256);
  const size_t fixed = 256;
  const size_t perrow = (size_t)256 * LDQ * 4;   // 1 MiB per srow
  size_t avail = ws_size > fixed ? ws_size - fixed : 0;
  int R = 256;
  while (R > 1 && (size_t)R * perrow > avail) R >>= 1;

  detect_mask<<<1, 256, 0, stream>>>((const unsigned char*)mask, flag);

  for (int c = 0; c < 256 / R; ++c) {
    const int srow0 = c * R;
    proj_qkvg<<<dim3(16, 2 * R), 256, 0, stream>>>(
        x + (size_t)srow0 * 256 * CIN, Wq, Wk, Wv, Wg, bg, qkvg);
    attn<<<dim3(NH, R), 256, 0, stream>>>(qkvg, bias, mask, flag, srow0);
    out_proj<<<dim3(2, 2 * R), 256, 0, stream>>>(
        qkvg, Wo, bo, out + (size_t)srow0 * 256 * CIN);
  }
}

// Round 4
// 458.529 us; speedup vs baseline: 1.6336x; 1.6336x over previous
//
#include <hip/hip_runtime.h>
#include <cstdint>

#define CIN 128
#define NH 8
#define CH 32
#define LDQ16 1024   // qkvg row stride in shorts: [q 256|k 256|v 256|g 256]

typedef short bf16x8 __attribute__((ext_vector_type(8)));
typedef float f32x4 __attribute__((ext_vector_type(4)));

__device__ __forceinline__ short f2bf(float f) {
  union { float f; unsigned u; } v; v.f = f;
  unsigned r = (v.u + 0x7FFFu + ((v.u >> 16) & 1u)) >> 16;   // RNE
  return (short)r;
}
__device__ __forceinline__ float bf2f(short s) {
  union { unsigned u; float f; } v; v.u = ((unsigned)(unsigned short)s) << 16;
  return v.f;
}

// ---------------- prep: weights -> bf16 transposed [n][k]; qscale folded ----------------
// WT: 1024 n x 128 k (q|k|v|g);  WoT: 128 n x 256 k
__global__ __launch_bounds__(256) void prep_w(
    const float* __restrict__ Wq, const float* __restrict__ Wk,
    const float* __restrict__ Wv, const float* __restrict__ Wg,
    const float* __restrict__ Wo, short* __restrict__ WT, short* __restrict__ WoT)
{
  const float qscale = 0.17677669529663689f;  // 1/sqrt(32)
#pragma unroll
  for (int e = 0; e < 10; ++e) {
    int o = blockIdx.x * 2560 + e * 256 + threadIdx.x;
    if (o < 131072) {
      int n = o >> 7, k = o & 127;
      int seg = n >> 8, nn = n & 255;
      const float* W = (seg == 0) ? Wq : (seg == 1) ? Wk : (seg == 2) ? Wv : Wg;
      float v = W[k * 256 + nn];
      if (seg == 0) v *= qscale;
      WT[o] = f2bf(v);
    } else {
      int o2 = o - 131072;
      int n = o2 >> 8, k = o2 & 255;
      WoT[o2] = f2bf(Wo[k * 128 + n]);
    }
  }
}

// ---------------- prep: x -> bf16 ----------------
__global__ __launch_bounds__(256) void prep_x(
    const float* __restrict__ x, short* __restrict__ xb)
{
  int base = (blockIdx.x * 256 + threadIdx.x) * 8;
  float4 a = *(const float4*)(x + base);
  float4 b = *(const float4*)(x + base + 4);
  bf16x8 r;
  r[0] = f2bf(a.x); r[1] = f2bf(a.y); r[2] = f2bf(a.z); r[3] = f2bf(a.w);
  r[4] = f2bf(b.x); r[5] = f2bf(b.y); r[6] = f2bf(b.z); r[7] = f2bf(b.w);
  *(bf16x8*)(xb + base) = r;
}

// ---------------- prep: detect mask element width (reads first 64KB only) ----------------
// int32 {0,1} data => every dword <= 1. uint8 0/1 data violates massively.
__global__ __launch_bounds__(256) void detect_mask(
    const uint4* __restrict__ m, unsigned int* __restrict__ flag)
{
  __shared__ int viol;
  if (threadIdx.x == 0) viol = 0;
  __syncthreads();
  int v = 0;
#pragma unroll
  for (int j = 0; j < 16; ++j) {
    uint4 w = m[j * 256 + threadIdx.x];
    v |= (w.x > 1u) | (w.y > 1u) | (w.z > 1u) | (w.w > 1u);
  }
  if (v) atomicOr(&viol, 1);
  __syncthreads();
  if (threadIdx.x == 0) *flag = viol ? 0u : 1u;
}

// ---------------- QKVG projection, bf16 MFMA ----------------
// C[65536 x 1024] = xb[65536 x 128] @ WT^T ; block = 64 rows x 128 cols, K=128 staged once.
// 4 waves in 2x2; wave = 32 rows x 64 cols = 2x4 tiles of 16x16, 4 k-steps.
__global__ __launch_bounds__(256) void proj_qkvg(
    const short* __restrict__ xb, const short* __restrict__ WT,
    const float* __restrict__ bg, short* __restrict__ qkvg)
{
  __shared__ short Al[64 * 136];    // [row][k], stride 136
  __shared__ short Bl[128 * 136];   // [n][k],  stride 136
  const int tid = threadIdx.x;
  const int lane = tid & 63, w = tid >> 6;
  const int g = lane >> 4, c16 = lane & 15;
  const int wr = w & 1, wc = w >> 1;
  const int n0 = blockIdx.x * 128;
  const int row0 = blockIdx.y * 64;

  {
    const short* src = xb + (size_t)row0 * 128;
#pragma unroll
    for (int ch = 0; ch < 4; ++ch) {
      int c = ch * 256 + tid;
      int r = c >> 4, kc = c & 15;
      *(bf16x8*)&Al[r * 136 + kc * 8] = *(const bf16x8*)(src + r * 128 + kc * 8);
    }
    const short* wsrc = WT + (size_t)n0 * 128;
#pragma unroll
    for (int ch = 0; ch < 8; ++ch) {
      int c = ch * 256 + tid;
      int r = c >> 4, kc = c & 15;
      *(bf16x8*)&Bl[r * 136 + kc * 8] = *(const bf16x8*)(wsrc + r * 128 + kc * 8);
    }
  }
  __syncthreads();

  f32x4 acc[2][4];
#pragma unroll
  for (int rt = 0; rt < 2; ++rt)
#pragma unroll
    for (int ct = 0; ct < 4; ++ct) acc[rt][ct] = (f32x4){0.f, 0.f, 0.f, 0.f};

#pragma unroll
  for (int kk = 0; kk < 4; ++kk) {
    bf16x8 af[2], bfr[4];
#pragma unroll
    for (int rt = 0; rt < 2; ++rt)
      af[rt] = *(const bf16x8*)&Al[(wr * 32 + rt * 16 + c16) * 136 + kk * 32 + g * 8];
#pragma unroll
    for (int ct = 0; ct < 4; ++ct)
      bfr[ct] = *(const bf16x8*)&Bl[(wc * 64 + ct * 16 + c16) * 136 + kk * 32 + g * 8];
#pragma unroll
    for (int rt = 0; rt < 2; ++rt)
#pragma unroll
      for (int ct = 0; ct < 4; ++ct)
        acc[rt][ct] = __builtin_amdgcn_mfma_f32_16x16x32_bf16(af[rt], bfr[ct], acc[rt][ct], 0, 0, 0);
  }

  const int seg3 = (n0 >= 768);
  float bgv[4];
  if (seg3) {
#pragma unroll
    for (int ct = 0; ct < 4; ++ct)
      bgv[ct] = bg[n0 - 768 + wc * 64 + ct * 16 + c16];
  }
#pragma unroll
  for (int rt = 0; rt < 2; ++rt)
#pragma unroll
    for (int ct = 0; ct < 4; ++ct) {
      int col = n0 + wc * 64 + ct * 16 + c16;
#pragma unroll
      for (int i = 0; i < 4; ++i) {
        int row = row0 + wr * 32 + rt * 16 + g * 4 + i;
        float v = acc[rt][ct][i];
        if (seg3) v = 1.f / (1.f + __expf(-(v + bgv[ct])));
        qkvg[(size_t)row * LDQ16 + col] = f2bf(v);
      }
    }
}

// ---------------- MFMA flash attention + gating (bf16 qkvg) ----------------
__global__ __launch_bounds__(256) void attn(
    short* __restrict__ qkvg, const float* __restrict__ bias,
    const void* __restrict__ maskraw, const unsigned int* __restrict__ flagp)
{
  // shorts: kL [256 keys][40] @0 ; vT [32 c][264] @10240 ; pL @18688 + w*2560
  __shared__ __align__(16) short lds16[28928];
  const int tid = threadIdx.x;
  const int h = blockIdx.x;
  const int srow = blockIdx.y;
  const int lane = tid & 63, w = tid >> 6;
  const int g = lane >> 4, c16 = lane & 15;
  short* rowbase = qkvg + (size_t)srow * (256 * LDQ16);

  // ---- mask row -> 8x u32 bits ----
  const unsigned int fl = *flagp;
  int mv = fl ? ((const int*)maskraw)[srow * 256 + tid]
              : (int)((const unsigned char*)maskraw)[srow * 256 + tid];
  unsigned long long bb = __ballot(mv != 0);
  unsigned int* scratch = (unsigned int*)&lds16[18688];
  if (lane == 0) {
    scratch[w * 2 + 0] = (unsigned int)bb;
    scratch[w * 2 + 1] = (unsigned int)(bb >> 32);
  }
  __syncthreads();
  unsigned int mb[8];
#pragma unroll
  for (int j = 0; j < 8; ++j) mb[j] = scratch[j];
  __syncthreads();

  // ---- stage k -> kL[key][c] (b128 copies), v -> vT[c][key] ----
#pragma unroll
  for (int ch = 0; ch < 4; ++ch) {
    int c = ch * 256 + tid;
    int key = c >> 2, cv = c & 3;
    const short* kp = rowbase + (size_t)key * LDQ16 + 256 + h * CH + cv * 8;
    *(bf16x8*)&lds16[key * 40 + cv * 8] = *(const bf16x8*)kp;
    bf16x8 vd = *(const bf16x8*)(kp + 256);
#pragma unroll
    for (int j = 0; j < 8; ++j)
      lds16[10240 + (cv * 8 + j) * 264 + key] = vd[j];
  }

  // ---- q A-frags direct from global bf16 ----
  const int qb = w * 64;
  bf16x8 qf[4];
#pragma unroll
  for (int rt = 0; rt < 4; ++rt)
    qf[rt] = *(const bf16x8*)(rowbase + (size_t)(qb + rt * 16 + c16) * LDQ16 + h * CH + g * 8);
  __syncthreads();

  const f32x4 zero4 = {0.f, 0.f, 0.f, 0.f};

  // ---- pass A: rowmax of raw QK^T ----
  float m_[4][4];
#pragma unroll
  for (int rt = 0; rt < 4; ++rt)
#pragma unroll
    for (int i = 0; i < 4; ++i) m_[rt][i] = -1e30f;

  for (int kt = 0; kt < 16; ++kt) {
    bf16x8 kf = *(const bf16x8*)&lds16[(kt * 16 + c16) * 40 + g * 8];
#pragma unroll
    for (int rt = 0; rt < 4; ++rt) {
      f32x4 S = __builtin_amdgcn_mfma_f32_16x16x32_bf16(qf[rt], kf, zero4, 0, 0, 0);
#pragma unroll
      for (int i = 0; i < 4; ++i) m_[rt][i] = fmaxf(m_[rt][i], S[i]);
    }
  }
#pragma unroll
  for (int rt = 0; rt < 4; ++rt)
#pragma unroll
    for (int i = 0; i < 4; ++i) {
      float v = m_[rt][i];
      v = fmaxf(v, __shfl_xor(v, 1));
      v = fmaxf(v, __shfl_xor(v, 2));
      v = fmaxf(v, __shfl_xor(v, 4));
      v = fmaxf(v, __shfl_xor(v, 8));
      m_[rt][i] = v;
    }

  // ---- pass B ----
  float l_[4][4];
#pragma unroll
  for (int rt = 0; rt < 4; ++rt)
#pragma unroll
    for (int i = 0; i < 4; ++i) l_[rt][i] = 0.f;
  f32x4 O[4][2];
#pragma unroll
  for (int rt = 0; rt < 4; ++rt) { O[rt][0] = zero4; O[rt][1] = zero4; }

  const int pbase = 18688 + w * 2560;
  const float* bh = bias + (size_t)h * 65536;

  for (int ch = 0; ch < 8; ++ch) {
#pragma unroll
    for (int t2 = 0; t2 < 2; ++t2) {
      const int kt = ch * 2 + t2;
      bf16x8 kf = *(const bf16x8*)&lds16[(kt * 16 + c16) * 40 + g * 8];
      const unsigned int bit = (mb[kt >> 1] >> (((kt & 1) << 4) + c16)) & 1u;
#pragma unroll
      for (int rt = 0; rt < 4; ++rt) {
        f32x4 S = __builtin_amdgcn_mfma_f32_16x16x32_bf16(qf[rt], kf, zero4, 0, 0, 0);
        const float* bp = bh + (size_t)(qb + rt * 16 + g * 4) * 256 + kt * 16 + c16;
#pragma unroll
        for (int i = 0; i < 4; ++i) {
          float s = S[i] + bp[i * 256];
          float p = bit ? __expf(s - m_[rt][i]) : 0.f;
          l_[rt][i] += p;
          lds16[pbase + (rt * 16 + g * 4 + i) * 40 + t2 * 16 + c16] = f2bf(p);
        }
      }
    }
    __syncthreads();
    bf16x8 vf0 = *(const bf16x8*)&lds16[10240 + (c16) * 264 + ch * 32 + g * 8];
    bf16x8 vf1 = *(const bf16x8*)&lds16[10240 + (16 + c16) * 264 + ch * 32 + g * 8];
#pragma unroll
    for (int rt = 0; rt < 4; ++rt) {
      bf16x8 pf = *(const bf16x8*)&lds16[pbase + (rt * 16 + c16) * 40 + g * 8];
      O[rt][0] = __builtin_amdgcn_mfma_f32_16x16x32_bf16(pf, vf0, O[rt][0], 0, 0, 0);
      O[rt][1] = __builtin_amdgcn_mfma_f32_16x16x32_bf16(pf, vf1, O[rt][1], 0, 0, 0);
    }
    __syncthreads();
  }

#pragma unroll
  for (int rt = 0; rt < 4; ++rt)
#pragma unroll
    for (int i = 0; i < 4; ++i) {
      float v = l_[rt][i];
      v += __shfl_xor(v, 1);
      v += __shfl_xor(v, 2);
      v += __shfl_xor(v, 4);
      v += __shfl_xor(v, 8);
      l_[rt][i] = v;
    }

  // ---- epilogue: O/l * gate -> q slot (bf16) ----
#pragma unroll
  for (int rt = 0; rt < 4; ++rt)
#pragma unroll
    for (int i = 0; i < 4; ++i) {
      float inv = 1.f / l_[rt][i];
      short* orow = rowbase + (size_t)(qb + rt * 16 + g * 4 + i) * LDQ16;
#pragma unroll
      for (int oc = 0; oc < 2; ++oc) {
        int c = oc * 16 + c16;
        float gv = bf2f(orow[768 + h * CH + c]);
        orow[h * CH + c] = f2bf(O[rt][oc][i] * inv * gv);
      }
    }
}

// ---------------- output projection: out = oG @ Wo + bo, bf16 MFMA ----------------
// block = 64 rows x 128 cols (full N), K=256 in 2 stages of 128.
__global__ __launch_bounds__(256) void out_proj(
    const short* __restrict__ og, const short* __restrict__ WoT,
    const float* __restrict__ bo, float* __restrict__ out)
{
  __shared__ short Al[64 * 136];
  __shared__ short Bl[128 * 136];
  const int tid = threadIdx.x;
  const int lane = tid & 63, w = tid >> 6;
  const int g = lane >> 4, c16 = lane & 15;
  const int wr = w & 1, wc = w >> 1;
  const int row0 = blockIdx.x * 64;

  f32x4 acc[2][4];
#pragma unroll
  for (int rt = 0; rt < 2; ++rt)
#pragma unroll
    for (int ct = 0; ct < 4; ++ct) acc[rt][ct] = (f32x4){0.f, 0.f, 0.f, 0.f};

  for (int kk0 = 0; kk0 < 256; kk0 += 128) {
#pragma unroll
    for (int ch = 0; ch < 4; ++ch) {
      int c = ch * 256 + tid;
      int r = c >> 4, kc = c & 15;
      *(bf16x8*)&Al[r * 136 + kc * 8] =
          *(const bf16x8*)(og + (size_t)(row0 + r) * LDQ16 + kk0 + kc * 8);
    }
#pragma unroll
    for (int ch = 0; ch < 8; ++ch) {
      int c = ch * 256 + tid;
      int r = c >> 4, kc = c & 15;
      *(bf16x8*)&Bl[r * 136 + kc * 8] =
          *(const bf16x8*)(WoT + (size_t)r * 256 + kk0 + kc * 8);
    }
    __syncthreads();
#pragma unroll
    for (int kk = 0; kk < 4; ++kk) {
      bf16x8 af[2], bfr[4];
#pragma unroll
      for (int rt = 0; rt < 2; ++rt)
        af[rt] = *(const bf16x8*)&Al[(wr * 32 + rt * 16 + c16) * 136 + kk * 32 + g * 8];
#pragma unroll
      for (int ct = 0; ct < 4; ++ct)
        bfr[ct] = *(const bf16x8*)&Bl[(wc * 64 + ct * 16 + c16) * 136 + kk * 32 + g * 8];
#pragma unroll
      for (int rt = 0; rt < 2; ++rt)
#pragma unroll
        for (int ct = 0; ct < 4; ++ct)
          acc[rt][ct] = __builtin_amdgcn_mfma_f32_16x16x32_bf16(af[rt], bfr[ct], acc[rt][ct], 0, 0, 0);
    }
    __syncthreads();
  }

#pragma unroll
  for (int rt = 0; rt < 2; ++rt)
#pragma unroll
    for (int ct = 0; ct < 4; ++ct) {
      int col = wc * 64 + ct * 16 + c16;
      float bv = bo[col];
#pragma unroll
      for (int i = 0; i < 4; ++i) {
        int row = row0 + wr * 32 + rt * 16 + g * 4 + i;
        out[(size_t)row * CIN + col] = acc[rt][ct][i] + bv;
      }
    }
}

extern "C" void kernel_launch(void* const* d_in, const int* in_sizes, int n_in,
                              void* d_out, int out_size, void* d_ws, size_t ws_size,
                              hipStream_t stream) {
  const float* x    = (const float*)d_in[0];
  const float* bias = (const float*)d_in[1];
  const void*  mask = d_in[2];
  const float* Wq   = (const float*)d_in[3];
  const float* Wk   = (const float*)d_in[4];
  const float* Wv   = (const float*)d_in[5];
  const float* Wo   = (const float*)d_in[6];
  const float* bo   = (const float*)d_in[7];
  const float* Wg   = (const float*)d_in[8];
  const float* bg   = (const float*)d_in[9];
  float* out = (float*)d_out;

  // ws: [flag 256B][WT 256KB][WoT 64KB][xb 16MB][qkvg bf16 128MB]  (~145MB; ws proven >=257MB)
  unsigned int* flag = (unsigned int*)d_ws;
  short* WT   = (short*)((char*)d_ws + 256);
  short* WoT  = WT + 131072;
  short* xb   = WoT + 32768;
  short* qkvg = xb + (size_t)65536 * 128;

  prep_w<<<64, 256, 0, stream>>>(Wq, Wk, Wv, Wg, Wo, WT, WoT);
  prep_x<<<4096, 256, 0, stream>>>(x, xb);
  detect_mask<<<1, 256, 0, stream>>>((const uint4*)mask, flag);
  proj_qkvg<<<dim3(8, 1024), 256, 0, stream>>>(xb, WT, bg, qkvg);
  attn<<<dim3(NH, 256), 256, 0, stream>>>(qkvg, bias, mask, flag);
  out_proj<<<1024, 256, 0, stream>>>(qkvg, WoT, bo, out);
}

// Round 5
// 285.910 us; speedup vs baseline: 2.6198x; 1.6038x over previous
//
#include <hip/hip_runtime.h>
#include <cstdint>

#define CIN 128
#define NH 8
#define CH 32
#define LDQ16 1024   // qkvg row stride in shorts: [q 256|k 256|v 256|g 256]

typedef short bf16x8 __attribute__((ext_vector_type(8)));
typedef float f32x4 __attribute__((ext_vector_type(4)));

__device__ __forceinline__ short f2bf(float f) {
  union { float f; unsigned u; } v; v.f = f;
  unsigned r = (v.u + 0x7FFFu + ((v.u >> 16) & 1u)) >> 16;   // RNE
  return (short)r;
}
__device__ __forceinline__ float bf2f(short s) {
  union { unsigned u; float f; } v; v.u = ((unsigned)(unsigned short)s) << 16;
  return v.f;
}

// ---------------- prep: weights -> bf16 transposed [n][k]; qscale folded ----------------
__global__ __launch_bounds__(256) void prep_w(
    const float* __restrict__ Wq, const float* __restrict__ Wk,
    const float* __restrict__ Wv, const float* __restrict__ Wg,
    const float* __restrict__ Wo, short* __restrict__ WT, short* __restrict__ WoT)
{
  const float qscale = 0.17677669529663689f;  // 1/sqrt(32)
#pragma unroll
  for (int e = 0; e < 10; ++e) {
    int o = blockIdx.x * 2560 + e * 256 + threadIdx.x;
    if (o < 131072) {
      int n = o >> 7, k = o & 127;
      int seg = n >> 8, nn = n & 255;
      const float* W = (seg == 0) ? Wq : (seg == 1) ? Wk : (seg == 2) ? Wv : Wg;
      float v = W[k * 256 + nn];
      if (seg == 0) v *= qscale;
      WT[o] = f2bf(v);
    } else {
      int o2 = o - 131072;
      int n = o2 >> 8, k = o2 & 255;
      WoT[o2] = f2bf(Wo[k * 128 + n]);
    }
  }
}

// ---------------- prep: x -> bf16 ----------------
__global__ __launch_bounds__(256) void prep_x(
    const float* __restrict__ x, short* __restrict__ xb)
{
  int base = (blockIdx.x * 256 + threadIdx.x) * 8;
  float4 a = *(const float4*)(x + base);
  float4 b = *(const float4*)(x + base + 4);
  bf16x8 r;
  r[0] = f2bf(a.x); r[1] = f2bf(a.y); r[2] = f2bf(a.z); r[3] = f2bf(a.w);
  r[4] = f2bf(b.x); r[5] = f2bf(b.y); r[6] = f2bf(b.z); r[7] = f2bf(b.w);
  *(bf16x8*)(xb + base) = r;
}

// ---------------- prep: detect mask element width (reads first 64KB only) ----------------
__global__ __launch_bounds__(256) void detect_mask(
    const uint4* __restrict__ m, unsigned int* __restrict__ flag)
{
  __shared__ int viol;
  if (threadIdx.x == 0) viol = 0;
  __syncthreads();
  int v = 0;
#pragma unroll
  for (int j = 0; j < 16; ++j) {
    uint4 w = m[j * 256 + threadIdx.x];
    v |= (w.x > 1u) | (w.y > 1u) | (w.z > 1u) | (w.w > 1u);
  }
  if (v) atomicOr(&viol, 1);
  __syncthreads();
  if (threadIdx.x == 0) *flag = viol ? 0u : 1u;
}

// ---------------- QKVG projection, bf16 MFMA ----------------
__global__ __launch_bounds__(256) void proj_qkvg(
    const short* __restrict__ xb, const short* __restrict__ WT,
    const float* __restrict__ bg, short* __restrict__ qkvg)
{
  __shared__ short Al[64 * 136];
  __shared__ short Bl[128 * 136];
  const int tid = threadIdx.x;
  const int lane = tid & 63, w = tid >> 6;
  const int g = lane >> 4, c16 = lane & 15;
  const int wr = w & 1, wc = w >> 1;
  const int n0 = blockIdx.x * 128;
  const int row0 = blockIdx.y * 64;

  {
    const short* src = xb + (size_t)row0 * 128;
#pragma unroll
    for (int ch = 0; ch < 4; ++ch) {
      int c = ch * 256 + tid;
      int r = c >> 4, kc = c & 15;
      *(bf16x8*)&Al[r * 136 + kc * 8] = *(const bf16x8*)(src + r * 128 + kc * 8);
    }
    const short* wsrc = WT + (size_t)n0 * 128;
#pragma unroll
    for (int ch = 0; ch < 8; ++ch) {
      int c = ch * 256 + tid;
      int r = c >> 4, kc = c & 15;
      *(bf16x8*)&Bl[r * 136 + kc * 8] = *(const bf16x8*)(wsrc + r * 128 + kc * 8);
    }
  }
  __syncthreads();

  f32x4 acc[2][4];
#pragma unroll
  for (int rt = 0; rt < 2; ++rt)
#pragma unroll
    for (int ct = 0; ct < 4; ++ct) acc[rt][ct] = (f32x4){0.f, 0.f, 0.f, 0.f};

#pragma unroll
  for (int kk = 0; kk < 4; ++kk) {
    bf16x8 af[2], bfr[4];
#pragma unroll
    for (int rt = 0; rt < 2; ++rt)
      af[rt] = *(const bf16x8*)&Al[(wr * 32 + rt * 16 + c16) * 136 + kk * 32 + g * 8];
#pragma unroll
    for (int ct = 0; ct < 4; ++ct)
      bfr[ct] = *(const bf16x8*)&Bl[(wc * 64 + ct * 16 + c16) * 136 + kk * 32 + g * 8];
#pragma unroll
    for (int rt = 0; rt < 2; ++rt)
#pragma unroll
      for (int ct = 0; ct < 4; ++ct)
        acc[rt][ct] = __builtin_amdgcn_mfma_f32_16x16x32_bf16(af[rt], bfr[ct], acc[rt][ct], 0, 0, 0);
  }

  const int seg3 = (n0 >= 768);
  float bgv[4];
  if (seg3) {
#pragma unroll
    for (int ct = 0; ct < 4; ++ct)
      bgv[ct] = bg[n0 - 768 + wc * 64 + ct * 16 + c16];
  }
#pragma unroll
  for (int rt = 0; rt < 2; ++rt)
#pragma unroll
    for (int ct = 0; ct < 4; ++ct) {
      int col = n0 + wc * 64 + ct * 16 + c16;
#pragma unroll
      for (int i = 0; i < 4; ++i) {
        int row = row0 + wr * 32 + rt * 16 + g * 4 + i;
        float v = acc[rt][ct][i];
        if (seg3) v = 1.f / (1.f + __expf(-(v + bgv[ct])));
        qkvg[(size_t)row * LDQ16 + col] = f2bf(v);
      }
    }
}

// ---------------- MFMA flash attention + gating (barrier-free main loop) ----------------
// LDS (shorts): kL [256 keys][40] @0 ; vT packed key-pairs as dwords,
// [32 c][132 dw] @10240 ; pL per-wave [64 q][40] @18688 + w*2560 ; scratch @28928.
__global__ __launch_bounds__(256) void attn(
    short* __restrict__ qkvg, const float* __restrict__ bias,
    const void* __restrict__ maskraw, const unsigned int* __restrict__ flagp)
{
  __shared__ __align__(16) short lds16[28944];
  const int tid = threadIdx.x;
  const int h = blockIdx.x;
  const int srow = blockIdx.y;
  const int lane = tid & 63, w = tid >> 6;
  const int g = lane >> 4, c16 = lane & 15;
  short* rowbase = qkvg + (size_t)srow * (256 * LDQ16);
  unsigned int* vTd = (unsigned int*)&lds16[10240];

  // ---- mask row -> 8x u32 bits into dedicated scratch ----
  const unsigned int fl = *flagp;
  int mv = fl ? ((const int*)maskraw)[srow * 256 + tid]
              : (int)((const unsigned char*)maskraw)[srow * 256 + tid];
  unsigned long long bb = __ballot(mv != 0);
  unsigned int* scratch = (unsigned int*)&lds16[28928];
  if (lane == 0) {
    scratch[w * 2 + 0] = (unsigned int)bb;
    scratch[w * 2 + 1] = (unsigned int)(bb >> 32);
  }

  // ---- stage k -> kL[key][c] (b128), v -> vTd packed key-pairs (b32) ----
#pragma unroll
  for (int it = 0; it < 2; ++it) {
    int c = it * 256 + tid;          // 0..511 = keypair(128) x cquad(4)
    int kp = c >> 2, cv = c & 3;
    const short* p0 = rowbase + (size_t)(2 * kp) * LDQ16 + 256 + h * CH + cv * 8;
    bf16x8 k0 = *(const bf16x8*)p0;
    bf16x8 k1 = *(const bf16x8*)(p0 + LDQ16);
    bf16x8 v0 = *(const bf16x8*)(p0 + 256);
    bf16x8 v1 = *(const bf16x8*)(p0 + LDQ16 + 256);
    *(bf16x8*)&lds16[(2 * kp) * 40 + cv * 8] = k0;
    *(bf16x8*)&lds16[(2 * kp + 1) * 40 + cv * 8] = k1;
#pragma unroll
    for (int j = 0; j < 8; ++j)
      vTd[(cv * 8 + j) * 132 + kp] =
          ((unsigned)(unsigned short)v0[j]) | (((unsigned)(unsigned short)v1[j]) << 16);
  }

  // ---- q A-frags direct from global bf16 ----
  const int qb = w * 64;
  bf16x8 qf[4];
#pragma unroll
  for (int rt = 0; rt < 4; ++rt)
    qf[rt] = *(const bf16x8*)(rowbase + (size_t)(qb + rt * 16 + c16) * LDQ16 + h * CH + g * 8);

  __syncthreads();   // the ONLY barrier: staging + mask scratch visible to all waves

  unsigned int mb[8];
#pragma unroll
  for (int j = 0; j < 8; ++j) mb[j] = scratch[j];

  const f32x4 zero4 = {0.f, 0.f, 0.f, 0.f};

  // ---- pass A: rowmax of raw QK^T (bias omitted: softmax shift-invariant) ----
  float m_[4][4];
#pragma unroll
  for (int rt = 0; rt < 4; ++rt)
#pragma unroll
    for (int i = 0; i < 4; ++i) m_[rt][i] = -1e30f;

  for (int kt = 0; kt < 16; ++kt) {
    bf16x8 kf = *(const bf16x8*)&lds16[(kt * 16 + c16) * 40 + g * 8];
#pragma unroll
    for (int rt = 0; rt < 4; ++rt) {
      f32x4 S = __builtin_amdgcn_mfma_f32_16x16x32_bf16(qf[rt], kf, zero4, 0, 0, 0);
#pragma unroll
      for (int i = 0; i < 4; ++i) m_[rt][i] = fmaxf(m_[rt][i], S[i]);
    }
  }
#pragma unroll
  for (int rt = 0; rt < 4; ++rt)
#pragma unroll
    for (int i = 0; i < 4; ++i) {
      float v = m_[rt][i];
      v = fmaxf(v, __shfl_xor(v, 1));
      v = fmaxf(v, __shfl_xor(v, 2));
      v = fmaxf(v, __shfl_xor(v, 4));
      v = fmaxf(v, __shfl_xor(v, 8));
      m_[rt][i] = v;
    }

  // ---- pass B: barrier-free (pL is per-wave private; kL/vT read-only) ----
  float l_[4][4];
#pragma unroll
  for (int rt = 0; rt < 4; ++rt)
#pragma unroll
    for (int i = 0; i < 4; ++i) l_[rt][i] = 0.f;
  f32x4 O[4][2];
#pragma unroll
  for (int rt = 0; rt < 4; ++rt) { O[rt][0] = zero4; O[rt][1] = zero4; }

  const int pbase = 18688 + w * 2560;
  const float* bh = bias + (size_t)h * 65536;

  for (int ch = 0; ch < 8; ++ch) {
    // prefetch this chunk's bias (32 scalars) before the MFMAs that precede use
    float bb_[2][4][4];
#pragma unroll
    for (int t2 = 0; t2 < 2; ++t2) {
      const int kt = ch * 2 + t2;
      const float* bp0 = bh + (size_t)qb * 256 + kt * 16 + c16;
#pragma unroll
      for (int rt = 0; rt < 4; ++rt)
#pragma unroll
        for (int i = 0; i < 4; ++i)
          bb_[t2][rt][i] = bp0[(size_t)(rt * 16 + g * 4 + i) * 256];
    }

#pragma unroll
    for (int t2 = 0; t2 < 2; ++t2) {
      const int kt = ch * 2 + t2;
      bf16x8 kf = *(const bf16x8*)&lds16[(kt * 16 + c16) * 40 + g * 8];
      const unsigned int bit = (mb[kt >> 1] >> (((kt & 1) << 4) + c16)) & 1u;
#pragma unroll
      for (int rt = 0; rt < 4; ++rt) {
        f32x4 S = __builtin_amdgcn_mfma_f32_16x16x32_bf16(qf[rt], kf, zero4, 0, 0, 0);
#pragma unroll
        for (int i = 0; i < 4; ++i) {
          float s = S[i] + bb_[t2][rt][i];
          float p = bit ? __expf(s - m_[rt][i]) : 0.f;
          l_[rt][i] += p;
          lds16[pbase + (rt * 16 + g * 4 + i) * 40 + t2 * 16 + c16] = f2bf(p);
        }
      }
    }
    // wave-local LDS write->read ordering is handled by lgkmcnt; no barrier
    bf16x8 vf0 = *(const bf16x8*)&vTd[(size_t)c16 * 132 + ch * 16 + g * 4];
    bf16x8 vf1 = *(const bf16x8*)&vTd[(size_t)(16 + c16) * 132 + ch * 16 + g * 4];
#pragma unroll
    for (int rt = 0; rt < 4; ++rt) {
      bf16x8 pf = *(const bf16x8*)&lds16[pbase + (rt * 16 + c16) * 40 + g * 8];
      O[rt][0] = __builtin_amdgcn_mfma_f32_16x16x32_bf16(pf, vf0, O[rt][0], 0, 0, 0);
      O[rt][1] = __builtin_amdgcn_mfma_f32_16x16x32_bf16(pf, vf1, O[rt][1], 0, 0, 0);
    }
  }

#pragma unroll
  for (int rt = 0; rt < 4; ++rt)
#pragma unroll
    for (int i = 0; i < 4; ++i) {
      float v = l_[rt][i];
      v += __shfl_xor(v, 1);
      v += __shfl_xor(v, 2);
      v += __shfl_xor(v, 4);
      v += __shfl_xor(v, 8);
      l_[rt][i] = v;
    }

  // ---- epilogue: O/l * gate -> q slot (bf16) ----
#pragma unroll
  for (int rt = 0; rt < 4; ++rt)
#pragma unroll
    for (int i = 0; i < 4; ++i) {
      float inv = 1.f / l_[rt][i];
      short* orow = rowbase + (size_t)(qb + rt * 16 + g * 4 + i) * LDQ16;
#pragma unroll
      for (int oc = 0; oc < 2; ++oc) {
        int c = oc * 16 + c16;
        float gv = bf2f(orow[768 + h * CH + c]);
        orow[h * CH + c] = f2bf(O[rt][oc][i] * inv * gv);
      }
    }
}

// ---------------- output projection: out = oG @ Wo + bo, bf16 MFMA ----------------
__global__ __launch_bounds__(256) void out_proj(
    const short* __restrict__ og, const short* __restrict__ WoT,
    const float* __restrict__ bo, float* __restrict__ out)
{
  __shared__ short Al[64 * 136];
  __shared__ short Bl[128 * 136];
  const int tid = threadIdx.x;
  const int lane = tid & 63, w = tid >> 6;
  const int g = lane >> 4, c16 = lane & 15;
  const int wr = w & 1, wc = w >> 1;
  const int row0 = blockIdx.x * 64;

  f32x4 acc[2][4];
#pragma unroll
  for (int rt = 0; rt < 2; ++rt)
#pragma unroll
    for (int ct = 0; ct < 4; ++ct) acc[rt][ct] = (f32x4){0.f, 0.f, 0.f, 0.f};

  for (int kk0 = 0; kk0 < 256; kk0 += 128) {
#pragma unroll
    for (int ch = 0; ch < 4; ++ch) {
      int c = ch * 256 + tid;
      int r = c >> 4, kc = c & 15;
      *(bf16x8*)&Al[r * 136 + kc * 8] =
          *(const bf16x8*)(og + (size_t)(row0 + r) * LDQ16 + kk0 + kc * 8);
    }
#pragma unroll
    for (int ch = 0; ch < 8; ++ch) {
      int c = ch * 256 + tid;
      int r = c >> 4, kc = c & 15;
      *(bf16x8*)&Bl[r * 136 + kc * 8] =
          *(const bf16x8*)(WoT + (size_t)r * 256 + kk0 + kc * 8);
    }
    __syncthreads();
#pragma unroll
    for (int kk = 0; kk < 4; ++kk) {
      bf16x8 af[2], bfr[4];
#pragma unroll
      for (int rt = 0; rt < 2; ++rt)
        af[rt] = *(const bf16x8*)&Al[(wr * 32 + rt * 16 + c16) * 136 + kk * 32 + g * 8];
#pragma unroll
      for (int ct = 0; ct < 4; ++ct)
        bfr[ct] = *(const bf16x8*)&Bl[(wc * 64 + ct * 16 + c16) * 136 + kk * 32 + g * 8];
#pragma unroll
      for (int rt = 0; rt < 2; ++rt)
#pragma unroll
        for (int ct = 0; ct < 4; ++ct)
          acc[rt][ct] = __builtin_amdgcn_mfma_f32_16x16x32_bf16(af[rt], bfr[ct], acc[rt][ct], 0, 0, 0);
    }
    __syncthreads();
  }

#pragma unroll
  for (int rt = 0; rt < 2; ++rt)
#pragma unroll
    for (int ct = 0; ct < 4; ++ct) {
      int col = wc * 64 + ct * 16 + c16;
      float bv = bo[col];
#pragma unroll
      for (int i = 0; i < 4; ++i) {
        int row = row0 + wr * 32 + rt * 16 + g * 4 + i;
        out[(size_t)row * CIN + col] = acc[rt][ct][i] + bv;
      }
    }
}

extern "C" void kernel_launch(void* const* d_in, const int* in_sizes, int n_in,
                              void* d_out, int out_size, void* d_ws, size_t ws_size,
                              hipStream_t stream) {
  const float* x    = (const float*)d_in[0];
  const float* bias = (const float*)d_in[1];
  const void*  mask = d_in[2];
  const float* Wq   = (const float*)d_in[3];
  const float* Wk   = (const float*)d_in[4];
  const float* Wv   = (const float*)d_in[5];
  const float* Wo   = (const float*)d_in[6];
  const float* bo   = (const float*)d_in[7];
  const float* Wg   = (const float*)d_in[8];
  const float* bg   = (const float*)d_in[9];
  float* out = (float*)d_out;

  // ws: [flag 256B][WT 256KB][WoT 64KB][xb 16MB][qkvg bf16 128MB]
  unsigned int* flag = (unsigned int*)d_ws;
  short* WT   = (short*)((char*)d_ws + 256);
  short* WoT  = WT + 131072;
  short* xb   = WoT + 32768;
  short* qkvg = xb + (size_t)65536 * 128;

  prep_w<<<64, 256, 0, stream>>>(Wq, Wk, Wv, Wg, Wo, WT, WoT);
  prep_x<<<4096, 256, 0, stream>>>(x, xb);
  detect_mask<<<1, 256, 0, stream>>>((const uint4*)mask, flag);
  proj_qkvg<<<dim3(8, 1024), 256, 0, stream>>>(xb, WT, bg, qkvg);
  attn<<<dim3(NH, 256), 256, 0, stream>>>(qkvg, bias, mask, flag);
  out_proj<<<1024, 256, 0, stream>>>(qkvg, WoT, bo, out);
}

// Round 6
// 274.740 us; speedup vs baseline: 2.7263x; 1.0407x over previous
//
#include <hip/hip_runtime.h>
#include <hip/hip_bf16.h>
#include <cstdint>

#define CIN 128
#define NH 8
#define CH 32
#define LDQ16 1024   // qkvg row stride in shorts: [q 256|k 256|v 256|g 256]

typedef short bf16x8 __attribute__((ext_vector_type(8)));
typedef float f32x4 __attribute__((ext_vector_type(4)));

__device__ __forceinline__ short f2bf(float f) {
  union { float f; unsigned u; } v; v.f = f;
  unsigned r = (v.u + 0x7FFFu + ((v.u >> 16) & 1u)) >> 16;   // RNE
  return (short)r;
}
__device__ __forceinline__ float bf2f(short s) {
  union { unsigned u; float f; } v; v.u = ((unsigned)(unsigned short)s) << 16;
  return v.f;
}
__device__ __forceinline__ unsigned pk2bf(float a, float b) {
  union { __hip_bfloat162 h; unsigned u; } cv;
  cv.h = __float22bfloat162_rn(make_float2(a, b));
  return cv.u;
}

// ---------------- merged prep: x->bf16 | weights->bf16 [n][k] | mask detect ----------------
// blocks 0..4095: xb ; 4096..4159: WT/WoT ; 4160: detect_mask
__global__ __launch_bounds__(256) void prep(
    const float* __restrict__ x,
    const float* __restrict__ Wq, const float* __restrict__ Wk,
    const float* __restrict__ Wv, const float* __restrict__ Wg,
    const float* __restrict__ Wo,
    const uint4* __restrict__ mask,
    short* __restrict__ xb, short* __restrict__ WT, short* __restrict__ WoT,
    unsigned int* __restrict__ flag)
{
  __shared__ int viol;
  const int b = blockIdx.x;
  if (b < 4096) {
    int base = (b * 256 + threadIdx.x) * 8;
    float4 a = *(const float4*)(x + base);
    float4 c = *(const float4*)(x + base + 4);
    bf16x8 r;
    r[0] = f2bf(a.x); r[1] = f2bf(a.y); r[2] = f2bf(a.z); r[3] = f2bf(a.w);
    r[4] = f2bf(c.x); r[5] = f2bf(c.y); r[6] = f2bf(c.z); r[7] = f2bf(c.w);
    *(bf16x8*)(xb + base) = r;
  } else if (b < 4160) {
    const float qscale = 0.17677669529663689f;  // 1/sqrt(32)
    int bb = b - 4096;
#pragma unroll
    for (int e = 0; e < 10; ++e) {
      int o = bb * 2560 + e * 256 + threadIdx.x;
      if (o < 131072) {
        int n = o >> 7, k = o & 127;
        int seg = n >> 8, nn = n & 255;
        const float* W = (seg == 0) ? Wq : (seg == 1) ? Wk : (seg == 2) ? Wv : Wg;
        float v = W[k * 256 + nn];
        if (seg == 0) v *= qscale;
        WT[o] = f2bf(v);
      } else {
        int o2 = o - 131072;
        int n = o2 >> 8, k = o2 & 255;
        WoT[o2] = f2bf(Wo[k * 128 + n]);
      }
    }
  } else {
    if (threadIdx.x == 0) viol = 0;
    __syncthreads();
    int v = 0;
#pragma unroll
    for (int j = 0; j < 16; ++j) {
      uint4 w = mask[j * 256 + threadIdx.x];
      v |= (w.x > 1u) | (w.y > 1u) | (w.z > 1u) | (w.w > 1u);
    }
    if (v) atomicOr(&viol, 1);
    __syncthreads();
    if (threadIdx.x == 0) *flag = viol ? 0u : 1u;
  }
}

// ---------------- QKVG projection, bf16 MFMA ----------------
__global__ __launch_bounds__(256) void proj_qkvg(
    const short* __restrict__ xb, const short* __restrict__ WT,
    const float* __restrict__ bg, short* __restrict__ qkvg)
{
  __shared__ short Al[64 * 136];
  __shared__ short Bl[128 * 136];
  const int tid = threadIdx.x;
  const int lane = tid & 63, w = tid >> 6;
  const int g = lane >> 4, c16 = lane & 15;
  const int wr = w & 1, wc = w >> 1;
  const int n0 = blockIdx.x * 128;
  const int row0 = blockIdx.y * 64;

  {
    const short* src = xb + (size_t)row0 * 128;
#pragma unroll
    for (int ch = 0; ch < 4; ++ch) {
      int c = ch * 256 + tid;
      int r = c >> 4, kc = c & 15;
      *(bf16x8*)&Al[r * 136 + kc * 8] = *(const bf16x8*)(src + r * 128 + kc * 8);
    }
    const short* wsrc = WT + (size_t)n0 * 128;
#pragma unroll
    for (int ch = 0; ch < 8; ++ch) {
      int c = ch * 256 + tid;
      int r = c >> 4, kc = c & 15;
      *(bf16x8*)&Bl[r * 136 + kc * 8] = *(const bf16x8*)(wsrc + r * 128 + kc * 8);
    }
  }
  __syncthreads();

  f32x4 acc[2][4];
#pragma unroll
  for (int rt = 0; rt < 2; ++rt)
#pragma unroll
    for (int ct = 0; ct < 4; ++ct) acc[rt][ct] = (f32x4){0.f, 0.f, 0.f, 0.f};

#pragma unroll
  for (int kk = 0; kk < 4; ++kk) {
    bf16x8 af[2], bfr[4];
#pragma unroll
    for (int rt = 0; rt < 2; ++rt)
      af[rt] = *(const bf16x8*)&Al[(wr * 32 + rt * 16 + c16) * 136 + kk * 32 + g * 8];
#pragma unroll
    for (int ct = 0; ct < 4; ++ct)
      bfr[ct] = *(const bf16x8*)&Bl[(wc * 64 + ct * 16 + c16) * 136 + kk * 32 + g * 8];
#pragma unroll
    for (int rt = 0; rt < 2; ++rt)
#pragma unroll
      for (int ct = 0; ct < 4; ++ct)
        acc[rt][ct] = __builtin_amdgcn_mfma_f32_16x16x32_bf16(af[rt], bfr[ct], acc[rt][ct], 0, 0, 0);
  }

  const int seg3 = (n0 >= 768);
  float bgv[4];
  if (seg3) {
#pragma unroll
    for (int ct = 0; ct < 4; ++ct)
      bgv[ct] = bg[n0 - 768 + wc * 64 + ct * 16 + c16];
  }
#pragma unroll
  for (int rt = 0; rt < 2; ++rt)
#pragma unroll
    for (int ct = 0; ct < 4; ++ct) {
      int col = n0 + wc * 64 + ct * 16 + c16;
#pragma unroll
      for (int i = 0; i < 4; ++i) {
        int row = row0 + wr * 32 + rt * 16 + g * 4 + i;
        float v = acc[rt][ct][i];
        if (seg3) v = 1.f / (1.f + __expf(-(v + bgv[ct])));
        qkvg[(size_t)row * LDQ16 + col] = f2bf(v);
      }
    }
}

// ---------------- MFMA flash attention, S^T formulation, single-pass ----------------
// S^T = K.Q^T via mfma(kf, qf): thread holds 4 consecutive KEYS at fixed q ->
// b64 P writes, float4 bias loads. No max pass (raw exp safe: |s|<~15, clamp 85).
// LDS shorts: kL@0 [256key][40]; vTd@10240 [32c][132]dw; pL@18688 +w*2560 [64q][40];
// lL@28928 (4w x 64 f32); mask@29440.
__global__ __launch_bounds__(256) void attn(
    short* __restrict__ qkvg, const float* __restrict__ bias,
    const void* __restrict__ maskraw, const unsigned int* __restrict__ flagp)
{
  __shared__ __align__(16) short lds16[29456];
  const int tid = threadIdx.x;
  const int h = blockIdx.x;
  const int srow = blockIdx.y;
  const int lane = tid & 63, w = tid >> 6;
  const int g = lane >> 4, c16 = lane & 15;
  short* rowbase = qkvg + (size_t)srow * (256 * LDQ16);
  unsigned int* vTd = (unsigned int*)&lds16[10240];
  float* lL = (float*)&lds16[28928];

  // ---- mask row -> 8x u32 bits ----
  const unsigned int fl = *flagp;
  int mv = fl ? ((const int*)maskraw)[srow * 256 + tid]
              : (int)((const unsigned char*)maskraw)[srow * 256 + tid];
  unsigned long long bb = __ballot(mv != 0);
  unsigned int* scratch = (unsigned int*)&lds16[29440];
  if (lane == 0) {
    scratch[w * 2 + 0] = (unsigned int)bb;
    scratch[w * 2 + 1] = (unsigned int)(bb >> 32);
  }

  // ---- stage k -> kL[key][c] (b128), v -> vTd packed key-pairs (b32) ----
#pragma unroll
  for (int it = 0; it < 2; ++it) {
    int c = it * 256 + tid;          // keypair(128) x cquad(4)
    int kp = c >> 2, cv = c & 3;
    const short* p0 = rowbase + (size_t)(2 * kp) * LDQ16 + 256 + h * CH + cv * 8;
    bf16x8 k0 = *(const bf16x8*)p0;
    bf16x8 k1 = *(const bf16x8*)(p0 + LDQ16);
    bf16x8 v0 = *(const bf16x8*)(p0 + 256);
    bf16x8 v1 = *(const bf16x8*)(p0 + LDQ16 + 256);
    *(bf16x8*)&lds16[(2 * kp) * 40 + cv * 8] = k0;
    *(bf16x8*)&lds16[(2 * kp + 1) * 40 + cv * 8] = k1;
#pragma unroll
    for (int j = 0; j < 8; ++j)
      vTd[(cv * 8 + j) * 132 + kp] =
          ((unsigned)(unsigned short)v0[j]) | (((unsigned)(unsigned short)v1[j]) << 16);
  }

  // ---- q B-frags direct from global bf16 (B[k=chan][n=q] wants [q][chan] layout) ----
  const int qb = w * 64;
  bf16x8 qf[4];
#pragma unroll
  for (int qt = 0; qt < 4; ++qt)
    qf[qt] = *(const bf16x8*)(rowbase + (size_t)(qb + qt * 16 + c16) * LDQ16 + h * CH + g * 8);

  __syncthreads();   // only barrier: staging + mask visible

  unsigned int mb[8];
#pragma unroll
  for (int j = 0; j < 8; ++j) mb[j] = scratch[j];

  const f32x4 zero4 = {0.f, 0.f, 0.f, 0.f};
  float l_[4] = {0.f, 0.f, 0.f, 0.f};
  f32x4 O[4][2];
#pragma unroll
  for (int qt = 0; qt < 4; ++qt) { O[qt][0] = zero4; O[qt][1] = zero4; }

  const int pbase = 18688 + w * 2560;
  const float* bh = bias + (size_t)h * 65536;

  for (int ch = 0; ch < 8; ++ch) {
    // prefetch bias: thread covers keys ch*32+kt*16+g*4.. (4 consecutive) at q=qt*16+c16
    float4 bb4[2][4];
#pragma unroll
    for (int kt = 0; kt < 2; ++kt)
#pragma unroll
      for (int qt = 0; qt < 4; ++qt)
        bb4[kt][qt] = *(const float4*)(bh + (size_t)(qb + qt * 16 + c16) * 256 +
                                       ch * 32 + kt * 16 + g * 4);

#pragma unroll
    for (int kt = 0; kt < 2; ++kt) {
      bf16x8 kf = *(const bf16x8*)&lds16[(kt * 16 + c16) * 40 + g * 8];
      // wait: kf must be keys ch*32+kt*16 .. +15
      kf = *(const bf16x8*)&lds16[(ch * 32 + kt * 16 + c16) * 40 + g * 8];
      const unsigned nib = (mb[ch] >> (kt * 16 + g * 4)) & 0xFu;
      float em[4];
#pragma unroll
      for (int i = 0; i < 4; ++i) em[i] = ((nib >> i) & 1u) ? 1.f : 0.f;
#pragma unroll
      for (int qt = 0; qt < 4; ++qt) {
        f32x4 S = __builtin_amdgcn_mfma_f32_16x16x32_bf16(kf, qf[qt], zero4, 0, 0, 0);
        float p0 = em[0] * __expf(fminf(S[0] + bb4[kt][qt].x, 85.f));
        float p1 = em[1] * __expf(fminf(S[1] + bb4[kt][qt].y, 85.f));
        float p2 = em[2] * __expf(fminf(S[2] + bb4[kt][qt].z, 85.f));
        float p3 = em[3] * __expf(fminf(S[3] + bb4[kt][qt].w, 85.f));
        l_[qt] += (p0 + p1) + (p2 + p3);
        uint2 pw;
        pw.x = pk2bf(p0, p1);
        pw.y = pk2bf(p2, p3);
        *(uint2*)&lds16[pbase + (qt * 16 + c16) * 40 + kt * 16 + g * 4] = pw;
      }
    }
    // PV: A = P [q][key] b128, B = V^T [chan][key] b128 (wave-local, no barrier)
    bf16x8 vf0 = *(const bf16x8*)&vTd[(size_t)c16 * 132 + ch * 16 + g * 4];
    bf16x8 vf1 = *(const bf16x8*)&vTd[(size_t)(16 + c16) * 132 + ch * 16 + g * 4];
#pragma unroll
    for (int qt = 0; qt < 4; ++qt) {
      bf16x8 pf = *(const bf16x8*)&lds16[pbase + (qt * 16 + c16) * 40 + g * 8];
      O[qt][0] = __builtin_amdgcn_mfma_f32_16x16x32_bf16(pf, vf0, O[qt][0], 0, 0, 0);
      O[qt][1] = __builtin_amdgcn_mfma_f32_16x16x32_bf16(pf, vf1, O[qt][1], 0, 0, 0);
    }
  }

  // ---- l reduction: sum over 4 g-groups; park per-wave in lL ----
#pragma unroll
  for (int qt = 0; qt < 4; ++qt) {
    float v = l_[qt];
    v += __shfl_xor(v, 16);
    v += __shfl_xor(v, 32);
    if (lane < 16) lL[w * 64 + qt * 16 + c16] = v;
  }

  // ---- epilogue: O/l * gate -> q slot (bf16) ----
#pragma unroll
  for (int qt = 0; qt < 4; ++qt)
#pragma unroll
    for (int i = 0; i < 4; ++i) {
      float l = lL[w * 64 + qt * 16 + g * 4 + i];
      float inv = 1.f / l;
      short* orow = rowbase + (size_t)(qb + qt * 16 + g * 4 + i) * LDQ16;
#pragma unroll
      for (int half = 0; half < 2; ++half) {
        int c = half * 16 + c16;
        float gv = bf2f(orow[768 + h * CH + c]);
        orow[h * CH + c] = f2bf(O[qt][half][i] * inv * gv);
      }
    }
}

// ---------------- output projection: out = oG @ Wo + bo, bf16 MFMA ----------------
__global__ __launch_bounds__(256) void out_proj(
    const short* __restrict__ og, const short* __restrict__ WoT,
    const float* __restrict__ bo, float* __restrict__ out)
{
  __shared__ short Al[64 * 136];
  __shared__ short Bl[128 * 136];
  const int tid = threadIdx.x;
  const int lane = tid & 63, w = tid >> 6;
  const int g = lane >> 4, c16 = lane & 15;
  const int wr = w & 1, wc = w >> 1;
  const int row0 = blockIdx.x * 64;

  f32x4 acc[2][4];
#pragma unroll
  for (int rt = 0; rt < 2; ++rt)
#pragma unroll
    for (int ct = 0; ct < 4; ++ct) acc[rt][ct] = (f32x4){0.f, 0.f, 0.f, 0.f};

  for (int kk0 = 0; kk0 < 256; kk0 += 128) {
#pragma unroll
    for (int ch = 0; ch < 4; ++ch) {
      int c = ch * 256 + tid;
      int r = c >> 4, kc = c & 15;
      *(bf16x8*)&Al[r * 136 + kc * 8] =
          *(const bf16x8*)(og + (size_t)(row0 + r) * LDQ16 + kk0 + kc * 8);
    }
#pragma unroll
    for (int ch = 0; ch < 8; ++ch) {
      int c = ch * 256 + tid;
      int r = c >> 4, kc = c & 15;
      *(bf16x8*)&Bl[r * 136 + kc * 8] =
          *(const bf16x8*)(WoT + (size_t)r * 256 + kk0 + kc * 8);
    }
    __syncthreads();
#pragma unroll
    for (int kk = 0; kk < 4; ++kk) {
      bf16x8 af[2], bfr[4];
#pragma unroll
      for (int rt = 0; rt < 2; ++rt)
        af[rt] = *(const bf16x8*)&Al[(wr * 32 + rt * 16 + c16) * 136 + kk * 32 + g * 8];
#pragma unroll
      for (int ct = 0; ct < 4; ++ct)
        bfr[ct] = *(const bf16x8*)&Bl[(wc * 64 + ct * 16 + c16) * 136 + kk * 32 + g * 8];
#pragma unroll
      for (int rt = 0; rt < 2; ++rt)
#pragma unroll
        for (int ct = 0; ct < 4; ++ct)
          acc[rt][ct] = __builtin_amdgcn_mfma_f32_16x16x32_bf16(af[rt], bfr[ct], acc[rt][ct], 0, 0, 0);
    }
    __syncthreads();
  }

#pragma unroll
  for (int rt = 0; rt < 2; ++rt)
#pragma unroll
    for (int ct = 0; ct < 4; ++ct) {
      int col = wc * 64 + ct * 16 + c16;
      float bv = bo[col];
#pragma unroll
      for (int i = 0; i < 4; ++i) {
        int row = row0 + wr * 32 + rt * 16 + g * 4 + i;
        out[(size_t)row * CIN + col] = acc[rt][ct][i] + bv;
      }
    }
}

extern "C" void kernel_launch(void* const* d_in, const int* in_sizes, int n_in,
                              void* d_out, int out_size, void* d_ws, size_t ws_size,
                              hipStream_t stream) {
  const float* x    = (const float*)d_in[0];
  const float* bias = (const float*)d_in[1];
  const void*  mask = d_in[2];
  const float* Wq   = (const float*)d_in[3];
  const float* Wk   = (const float*)d_in[4];
  const float* Wv   = (const float*)d_in[5];
  const float* Wo   = (const float*)d_in[6];
  const float* bo   = (const float*)d_in[7];
  const float* Wg   = (const float*)d_in[8];
  const float* bg   = (const float*)d_in[9];
  float* out = (float*)d_out;

  // ws: [flag 256B][WT 256KB][WoT 64KB][xb 16MB][qkvg bf16 128MB]
  unsigned int* flag = (unsigned int*)d_ws;
  short* WT   = (short*)((char*)d_ws + 256);
  short* WoT  = WT + 131072;
  short* xb   = WoT + 32768;
  short* qkvg = xb + (size_t)65536 * 128;

  prep<<<4161, 256, 0, stream>>>(x, Wq, Wk, Wv, Wg, Wo, (const uint4*)mask,
                                 xb, WT, WoT, flag);
  proj_qkvg<<<dim3(8, 1024), 256, 0, stream>>>(xb, WT, bg, qkvg);
  attn<<<dim3(NH, 256), 256, 0, stream>>>(qkvg, bias, mask, flag);
  out_proj<<<1024, 256, 0, stream>>>(qkvg, WoT, bo, out);
}